// Round 5
// baseline (2070.743 us; speedup 1.0000x reference)
//
#include <hip/hip_runtime.h>
#include <math.h>

typedef __attribute__((ext_vector_type(8))) short bf16x8;
typedef __attribute__((ext_vector_type(4))) float f32x4;

constexpr int NB = 512;
constexpr int NS = 140;
constexpr int NH = 512;
constexpr int NE = 256;
constexpr int NV = 1000;
constexpr int NVP = 1024;   // padded vocab cols
constexpr int NT = 21;
constexpr int ND = 7;
constexpr int DL = 20;
constexpr int SOS = 2;
constexpr int LSTR = NT + 1;

// mega_step grid layout
constexpr int O_DAY = 0,    N_DAY = 3584;
constexpr int O_UG  = 3584, N_UG  = 128;
constexpr int O_HW  = 3712, N_HW  = 64;
constexpr int O_CC  = 3776, N_CC  = 32;
constexpr int O_AG  = 3808, N_AG  = 64;
constexpr int O_LG  = 3872, N_LG  = 128;
constexpr int O_LS  = 4000, N_LS  = 512;
constexpr int GRID  = 4512;

__device__ __forceinline__ unsigned short f2bf(float f) {
  union { float f; unsigned u; } v; v.f = f;
  unsigned r = v.u + 0x7fffu + ((v.u >> 16) & 1u);
  return (unsigned short)(r >> 16);
}
__device__ __forceinline__ float bf2f(unsigned short h) {
  union { unsigned u; float f; } v; v.u = ((unsigned)h) << 16;
  return v.f;
}
__device__ __forceinline__ float sigm(float x) { return 1.f / (1.f + expf(-x)); }
// biases pre-folded: sr = gi_r + gh_r, sz = gi_z + gh_z, n = tanh(gi_n + r*gh_n)
__device__ __forceinline__ float gru_one(float sr, float sz, float gn, float hn,
                                         float ho) {
  const float r = sigm(sr);
  const float z = sigm(sz);
  const float n = tanhf(gn + r * hn);
  return (1.f - z) * n + z * ho;
}

// ---------------------------------------------------------------------------
// 64x64 MFMA tile body (full tiles). A16: bf16 A. EPI: 0 none, 1 +bias
// (guarded col<NV), 2 tanh. OUT16: bf16 out.
// ---------------------------------------------------------------------------
template<int A16, int EPI, int OUT16>
__device__ __forceinline__ void gemm_body(
    const float* __restrict__ Af, const unsigned short* __restrict__ Ah,
    const unsigned short* __restrict__ Bt, const float* __restrict__ bias,
    float* __restrict__ C, unsigned short* __restrict__ C16,
    int K, int lda, int ldc, int bx, int by,
    unsigned short* As, unsigned short* Bs)
{
  const int tid = threadIdx.x;
  const int rowBase = by * 64, colBase = bx * 64;
  const int wave = tid >> 6, lane = tid & 63, quad = lane >> 4, l15 = lane & 15;
  const int rw = (wave & 1) * 32, cw = (wave >> 1) * 32;

  f32x4 acc[2][2];
#pragma unroll
  for (int i = 0; i < 2; ++i)
#pragma unroll
    for (int j = 0; j < 2; ++j)
#pragma unroll
      for (int r = 0; r < 4; ++r) acc[i][j][r] = 0.f;

  const int ar = tid >> 2;
  const int kq = (tid & 3) * 8;
  const float* aptrf = nullptr;
  const unsigned short* aptrh = nullptr;
  if (A16) aptrh = Ah + (size_t)(rowBase + ar) * lda + kq;
  else     aptrf = Af + (size_t)(rowBase + ar) * lda + kq;
  const unsigned short* bptr = Bt + (size_t)(colBase + ar) * K + kq;
  unsigned short* asd = &As[ar * 40 + kq];
  unsigned short* bsd = &Bs[ar * 40 + kq];

  float4 x0, x1;
  uint4 av;
  if (A16) {
    av = *(const uint4*)aptrh;
  } else {
    x0 = *(const float4*)aptrf; x1 = *(const float4*)(aptrf + 4);
  }
  uint4 bv = *(const uint4*)bptr;

  for (int k0 = 0; k0 < K; k0 += 32) {
    uint4 aw;
    if (A16) {
      aw = av;
    } else {
      aw.x = (unsigned)f2bf(x0.x) | ((unsigned)f2bf(x0.y) << 16);
      aw.y = (unsigned)f2bf(x0.z) | ((unsigned)f2bf(x0.w) << 16);
      aw.z = (unsigned)f2bf(x1.x) | ((unsigned)f2bf(x1.y) << 16);
      aw.w = (unsigned)f2bf(x1.z) | ((unsigned)f2bf(x1.w) << 16);
    }
    *(uint4*)asd = aw;
    *(uint4*)bsd = bv;
    __syncthreads();

    const int kn = k0 + 32;
    if (kn < K) {
      if (A16) {
        av = *(const uint4*)(aptrh + kn);
      } else {
        x0 = *(const float4*)(aptrf + kn);
        x1 = *(const float4*)(aptrf + kn + 4);
      }
      bv = *(const uint4*)(bptr + kn);
    }

    const bf16x8 af0 = *(const bf16x8*)&As[(rw + l15) * 40 + quad * 8];
    const bf16x8 af1 = *(const bf16x8*)&As[(rw + 16 + l15) * 40 + quad * 8];
    const bf16x8 bf0 = *(const bf16x8*)&Bs[(cw + l15) * 40 + quad * 8];
    const bf16x8 bf1 = *(const bf16x8*)&Bs[(cw + 16 + l15) * 40 + quad * 8];
    acc[0][0] = __builtin_amdgcn_mfma_f32_16x16x32_bf16(af0, bf0, acc[0][0], 0, 0, 0);
    acc[0][1] = __builtin_amdgcn_mfma_f32_16x16x32_bf16(af0, bf1, acc[0][1], 0, 0, 0);
    acc[1][0] = __builtin_amdgcn_mfma_f32_16x16x32_bf16(af1, bf0, acc[1][0], 0, 0, 0);
    acc[1][1] = __builtin_amdgcn_mfma_f32_16x16x32_bf16(af1, bf1, acc[1][1], 0, 0, 0);
    __syncthreads();
  }

#pragma unroll
  for (int i = 0; i < 2; ++i) {
    const int grow = rowBase + rw + 16 * i + quad * 4;
#pragma unroll
    for (int j = 0; j < 2; ++j) {
      const int gcol = colBase + cw + 16 * j + l15;
#pragma unroll
      for (int r = 0; r < 4; ++r) {
        float vo = acc[i][j][r];
        if (EPI == 1) vo += (gcol < NV) ? bias[gcol] : 0.f;
        if (EPI == 2) vo = tanhf(vo);
        if (OUT16) C16[(size_t)(grow + r) * ldc + gcol] = f2bf(vo);
        else       C[(size_t)(grow + r) * ldc + gcol] = vo;
      }
    }
  }
}

// ---------------------------------------------------------------------------
// One launch per pipeline iteration i:
//   day_i | ug_{i+1} (GRU-on-the-fly A) | hWrite_{i+1} | ctxcat_{i-1}
//   | aGEMM_{i-2} | logits_{i-3} | lsm_{i-4}
// All phases depend only on products of launch i-1 (double-buffered).
// ---------------------------------------------------------------------------
__global__ __launch_bounds__(256) void mega_step(
    const unsigned short* __restrict__ enc16, const int* __restrict__ numpairs,
    const unsigned short* __restrict__ W1t, const float* __restrict__ biasUG,
    const unsigned short* __restrict__ GiT,
    const float* __restrict__ ugRead, float* __restrict__ ugWrite,
    const float* __restrict__ hRead, float* __restrict__ hWrite,
    const float* __restrict__ weekRead, float* __restrict__ weekWrite,
    const unsigned short* __restrict__ ccRead, unsigned short* __restrict__ ccWrite,
    const unsigned short* __restrict__ W3t,
    const unsigned short* __restrict__ aRead, unsigned short* __restrict__ aWrite,
    const unsigned short* __restrict__ W4t, const float* __restrict__ fc_b,
    const float* __restrict__ lgRead, float* __restrict__ lgWrite,
    float* __restrict__ out, int tOut,
    int g1, int g1plain, int g2, int g3, int g4, int g5, int g6, int g7)
{
  __shared__ __align__(16) char smem[23040];
  const int blk = blockIdx.x;
  const int tid = threadIdx.x;
  const int wave = tid >> 6, lane = tid & 63, quad = lane >> 4, l15 = lane & 15;

  if (blk < O_UG) {
    // ================= DAY ATTENTION (step i) =================
    if (!g3) return;
    unsigned short* encs = (unsigned short*)smem;          // 20480 B
    float* uS  = (float*)(smem + 20480);                   // 2048 B
    float* scD = (float*)(smem + 22528);                   // 80 B
    float* wdD = (float*)(smem + 22608);                   // 80 B
    const int bd = blk - O_DAY;
    const int b = bd / ND, d = bd % ND;

    const uint4* ep = (const uint4*)(enc16 + ((size_t)b * NS + d * DL) * NH);
    uint4* dst = (uint4*)encs;
    for (int i = tid; i < DL * NH / 8; i += 256) dst[i] = ep[i];
    if (tid < NH / 4)
      ((float4*)uS)[tid] = ((const float4*)(ugRead + (size_t)b * 2048))[tid];
    __syncthreads();

    float u8[8];
    {
      float4 a = *(const float4*)(uS + lane * 8);
      float4 c = *(const float4*)(uS + lane * 8 + 4);
      u8[0] = a.x; u8[1] = a.y; u8[2] = a.z; u8[3] = a.w;
      u8[4] = c.x; u8[5] = c.y; u8[6] = c.z; u8[7] = c.w;
    }
#pragma unroll
    for (int si = 0; si < 5; ++si) {
      const int s = wave * 5 + si;
      const bf16x8 ev = *(const bf16x8*)&encs[s * NH + lane * 8];
      float p = 0.f;
#pragma unroll
      for (int j = 0; j < 8; ++j) p += bf2f((unsigned short)ev[j]) * u8[j];
#pragma unroll
      for (int off = 32; off; off >>= 1) p += __shfl_down(p, off);
      if (lane == 0) scD[s] = p;
    }
    __syncthreads();
    if (tid == 0) {
      float sc[DL], mx = -1e30f;
      for (int s = 0; s < DL; ++s) {
        float v = (numpairs[b * NS + d * DL + s] != 0) ? scD[s] : -1e9f;
        sc[s] = v; mx = fmaxf(mx, v);
      }
      float sum = 0.f;
      for (int s = 0; s < DL; ++s) { float e = expf(sc[s] - mx); sc[s] = e; sum += e; }
      const float inv = 1.f / sum;
      for (int s = 0; s < DL; ++s) wdD[s] = sc[s] * inv;
    }
    __syncthreads();
    float a0 = 0.f, a1 = 0.f;
#pragma unroll
    for (int s = 0; s < DL; ++s) {
      const float w = wdD[s];
      const unsigned pv = *(const unsigned*)&encs[s * NH + tid * 2];
      a0 += w * bf2f((unsigned short)(pv & 0xffffu));
      a1 += w * bf2f((unsigned short)(pv >> 16));
    }
    float2 r; r.x = a0; r.y = a1;
    *(float2*)(weekWrite + ((size_t)b * ND + d) * NH + tid * 2) = r;
  } else if (blk < O_HW) {
    // ================= ug_{i+1} GEMM, GRU-on-the-fly A (64x128 tiles) ======
    if (!g1) return;
    unsigned short* As = (unsigned short*)smem;            // 64*40*2 = 5120
    unsigned short* Bs = (unsigned short*)(smem + 5120);   // 128*40*2 = 10240
    const int id = blk - O_UG;
    const int bx = id & 15, by = id >> 4;
    const int rowBase = by * 64, colBase = bx * 128;

    f32x4 acc[2][4];
#pragma unroll
    for (int r = 0; r < 2; ++r)
#pragma unroll
      for (int c = 0; c < 4; ++c)
#pragma unroll
        for (int q = 0; q < 4; ++q) acc[r][c][q] = 0.f;

    const int ar = tid >> 2, kq = (tid & 3) * 8;
    const int b = rowBase + ar;
    const unsigned short* giRow = GiT + (size_t)b * 1536;
    const float* ugRow = ugRead + (size_t)b * 2048;
    const float* hRow  = hRead + (size_t)b * 512;
    const int bn = tid >> 1, bkq = (tid & 1) * 16;
    const unsigned short* bptr = W1t + (size_t)(colBase + bn) * 512 + bkq;
    unsigned short* asd = &As[ar * 40 + kq];
    unsigned short* bsd = &Bs[bn * 40 + bkq];

    ushort4 gR[2], gZ[2], gN[2];
    float4 fR[2], fZ[2], fN[2], fO[2];
#pragma unroll
    for (int hh = 0; hh < 2; ++hh) {
      const int j = kq + hh * 4;
      fO[hh] = *(const float4*)(hRow + j);
      if (!g1plain) {
        gR[hh] = *(const ushort4*)(giRow + j);
        gZ[hh] = *(const ushort4*)(giRow + 512 + j);
        gN[hh] = *(const ushort4*)(giRow + 1024 + j);
        fR[hh] = *(const float4*)(ugRow + 512 + j);
        fZ[hh] = *(const float4*)(ugRow + 1024 + j);
        fN[hh] = *(const float4*)(ugRow + 1536 + j);
      }
    }
    uint4 bv0 = *(const uint4*)bptr;
    uint4 bv1 = *(const uint4*)(bptr + 8);

    const int rw = (wave & 1) * 32, cw = (wave >> 1) * 64;

    for (int k0 = 0; k0 < 512; k0 += 32) {
      float hv[8];
#pragma unroll
      for (int hh = 0; hh < 2; ++hh) {
        if (g1plain) {
          hv[hh * 4 + 0] = fO[hh].x; hv[hh * 4 + 1] = fO[hh].y;
          hv[hh * 4 + 2] = fO[hh].z; hv[hh * 4 + 3] = fO[hh].w;
        } else {
          hv[hh * 4 + 0] = gru_one(bf2f(gR[hh].x) + fR[hh].x,
                                   bf2f(gZ[hh].x) + fZ[hh].x,
                                   bf2f(gN[hh].x), fN[hh].x, fO[hh].x);
          hv[hh * 4 + 1] = gru_one(bf2f(gR[hh].y) + fR[hh].y,
                                   bf2f(gZ[hh].y) + fZ[hh].y,
                                   bf2f(gN[hh].y), fN[hh].y, fO[hh].y);
          hv[hh * 4 + 2] = gru_one(bf2f(gR[hh].z) + fR[hh].z,
                                   bf2f(gZ[hh].z) + fZ[hh].z,
                                   bf2f(gN[hh].z), fN[hh].z, fO[hh].z);
          hv[hh * 4 + 3] = gru_one(bf2f(gR[hh].w) + fR[hh].w,
                                   bf2f(gZ[hh].w) + fZ[hh].w,
                                   bf2f(gN[hh].w), fN[hh].w, fO[hh].w);
        }
      }
      uint4 av;
      av.x = (unsigned)f2bf(hv[0]) | ((unsigned)f2bf(hv[1]) << 16);
      av.y = (unsigned)f2bf(hv[2]) | ((unsigned)f2bf(hv[3]) << 16);
      av.z = (unsigned)f2bf(hv[4]) | ((unsigned)f2bf(hv[5]) << 16);
      av.w = (unsigned)f2bf(hv[6]) | ((unsigned)f2bf(hv[7]) << 16);
      *(uint4*)asd = av;
      *(uint4*)bsd = bv0;
      *(uint4*)(bsd + 8) = bv1;
      __syncthreads();

      const int kn = k0 + 32;
      if (kn < 512) {
#pragma unroll
        for (int hh = 0; hh < 2; ++hh) {
          const int j = kn + kq + hh * 4;
          fO[hh] = *(const float4*)(hRow + j);
          if (!g1plain) {
            gR[hh] = *(const ushort4*)(giRow + j);
            gZ[hh] = *(const ushort4*)(giRow + 512 + j);
            gN[hh] = *(const ushort4*)(giRow + 1024 + j);
            fR[hh] = *(const float4*)(ugRow + 512 + j);
            fZ[hh] = *(const float4*)(ugRow + 1024 + j);
            fN[hh] = *(const float4*)(ugRow + 1536 + j);
          }
        }
        bv0 = *(const uint4*)(bptr + kn);
        bv1 = *(const uint4*)(bptr + kn + 8);
      }

      const bf16x8 af0 = *(const bf16x8*)&As[(rw + l15) * 40 + quad * 8];
      const bf16x8 af1 = *(const bf16x8*)&As[(rw + 16 + l15) * 40 + quad * 8];
#pragma unroll
      for (int c = 0; c < 4; ++c) {
        const bf16x8 bf = *(const bf16x8*)&Bs[(cw + c * 16 + l15) * 40 + quad * 8];
        acc[0][c] = __builtin_amdgcn_mfma_f32_16x16x32_bf16(af0, bf, acc[0][c], 0, 0, 0);
        acc[1][c] = __builtin_amdgcn_mfma_f32_16x16x32_bf16(af1, bf, acc[1][c], 0, 0, 0);
      }
      __syncthreads();
    }

#pragma unroll
    for (int r = 0; r < 2; ++r) {
      const int grow = rowBase + rw + 16 * r + quad * 4;
#pragma unroll
      for (int c = 0; c < 4; ++c) {
        const int gcol = colBase + cw + 16 * c + l15;
        const float bb = biasUG[gcol];
#pragma unroll
        for (int rr = 0; rr < 4; ++rr)
          ugWrite[(size_t)(grow + rr) * 2048 + gcol] = acc[r][c][rr] + bb;
      }
    }
  } else if (blk < O_CC) {
    // ================= h_{i+1} materialize =================
    if (!g2) return;
    const int base = (blk - O_HW) * 256 + tid;
    for (int v = base; v < 65536; v += N_HW * 256) {
      const int b = v >> 7;
      const int j = (v & 127) * 4;
      const unsigned short* giRow = GiT + (size_t)b * 1536 + j;
      const float* ugRow = ugRead + (size_t)b * 2048 + j;
      ushort4 gr = *(const ushort4*)(giRow);
      ushort4 gz = *(const ushort4*)(giRow + 512);
      ushort4 gn = *(const ushort4*)(giRow + 1024);
      float4 fr = *(const float4*)(ugRow + 512);
      float4 fz = *(const float4*)(ugRow + 1024);
      float4 fn = *(const float4*)(ugRow + 1536);
      float4 fo = *(const float4*)(hRead + (size_t)b * 512 + j);
      float4 r;
      r.x = gru_one(bf2f(gr.x) + fr.x, bf2f(gz.x) + fz.x, bf2f(gn.x), fn.x, fo.x);
      r.y = gru_one(bf2f(gr.y) + fr.y, bf2f(gz.y) + fz.y, bf2f(gn.y), fn.y, fo.y);
      r.z = gru_one(bf2f(gr.z) + fr.z, bf2f(gz.z) + fz.z, bf2f(gn.z), fn.z, fo.z);
      r.w = gru_one(bf2f(gr.w) + fr.w, bf2f(gz.w) + fz.w, bf2f(gn.w), fn.w, fo.w);
      *(float4*)(hWrite + (size_t)b * 512 + j) = r;
    }
  } else if (blk < O_AG) {
    // ================= ctx + concat (step i-1) =================
    if (!g4) return;
    float* scS = (float*)smem;
    float* awS = (float*)(smem + 448);
    const int rbase = (blk - O_CC) * 16;
    const int b16 = tid >> 4, k16 = tid & 15;
    const int b = rbase + b16;
    const float* vrow = ugRead + (size_t)b * 2048;     // v_{i-1} = u_i
    const float* wrow = weekRead + (size_t)b * ND * NH;

    for (int d = 0; d < ND; ++d) {
      const float* vp = vrow + k16 * 32;
      const float* wp = wrow + d * NH + k16 * 32;
      float p = 0.f;
#pragma unroll
      for (int q = 0; q < 8; ++q) {
        float4 a = *(const float4*)(vp + q * 4);
        float4 c = *(const float4*)(wp + q * 4);
        p += a.x * c.x + a.y * c.y + a.z * c.z + a.w * c.w;
      }
      p += __shfl_down(p, 8); p += __shfl_down(p, 4);
      p += __shfl_down(p, 2); p += __shfl_down(p, 1);
      if (k16 == 0) scS[b16 * ND + d] = p;
    }
    __syncthreads();
    if (tid < 16) {
      float s[ND], mx = -1e30f;
      for (int d = 0; d < ND; ++d) { s[d] = scS[tid * ND + d]; mx = fmaxf(mx, s[d]); }
      float sum = 0.f;
      for (int d = 0; d < ND; ++d) { float e = expf(s[d] - mx); s[d] = e; sum += e; }
      const float inv = 1.f / sum;
      for (int d = 0; d < ND; ++d) awS[tid * ND + d] = s[d] * inv;
    }
    __syncthreads();

    const int c0 = k16 * 32;
    const float* hp = hRead + (size_t)b * NH + c0;     // h_i
    float aw[ND];
#pragma unroll
    for (int d = 0; d < ND; ++d) aw[d] = awS[b16 * ND + d];
    unsigned short* crow = ccWrite + (size_t)b * 1024;
#pragma unroll
    for (int q = 0; q < 8; ++q) {
      const int c = c0 + q * 4;
      float4 hv = *(const float4*)(hp + q * 4);
      ushort4 hs;
      hs.x = f2bf(hv.x); hs.y = f2bf(hv.y); hs.z = f2bf(hv.z); hs.w = f2bf(hv.w);
      *(ushort4*)(crow + c) = hs;
      float4 cv = make_float4(0.f, 0.f, 0.f, 0.f);
#pragma unroll
      for (int d = 0; d < ND; ++d) {
        float4 wv = *(const float4*)(wrow + d * NH + c);
        cv.x += aw[d] * wv.x; cv.y += aw[d] * wv.y;
        cv.z += aw[d] * wv.z; cv.w += aw[d] * wv.w;
      }
      ushort4 cs;
      cs.x = f2bf(cv.x); cs.y = f2bf(cv.y); cs.z = f2bf(cv.z); cs.w = f2bf(cv.w);
      *(ushort4*)(crow + 512 + c) = cs;
    }
  } else if (blk < O_LG) {
    // ================= a = tanh(concat @ W3^T) (step i-2) =================
    if (!g5) return;
    const int id = blk - O_AG;
    gemm_body<1, 2, 1>(nullptr, ccRead, W3t, nullptr, nullptr, aWrite,
                       1024, 1024, 512, id & 7, id >> 3,
                       (unsigned short*)smem, (unsigned short*)(smem + 5120));
  } else if (blk < O_LS) {
    // ================= logits = a @ W4^T + b (step i-3) =================
    if (!g6) return;
    const int id = blk - O_LG;
    gemm_body<1, 1, 0>(nullptr, aRead, W4t, fc_b, lgWrite, nullptr,
                       512, 512, NVP, id & 15, id >> 4,
                       (unsigned short*)smem, (unsigned short*)(smem + 5120));
  } else {
    // ================= log_softmax (step i-4) =================
    if (!g7) return;
    float* redm = (float*)smem;
    float* reds = (float*)(smem + 64);
    const int b = blk - O_LS;
    const float* row = lgRead + (size_t)b * NVP;
    float* orow = out + (size_t)b * NT * NV + (size_t)tOut * NV;

    float mx = -1e30f;
    for (int v = tid; v < NV; v += 256) mx = fmaxf(mx, row[v]);
#pragma unroll
    for (int off = 32; off; off >>= 1) mx = fmaxf(mx, __shfl_down(mx, off));
    if (lane == 0) redm[wave] = mx;
    __syncthreads();
    if (tid == 0) redm[0] = fmaxf(fmaxf(redm[0], redm[1]), fmaxf(redm[2], redm[3]));
    __syncthreads();
    mx = redm[0];

    float s = 0.f;
    for (int v = tid; v < NV; v += 256) s += expf(row[v] - mx);
#pragma unroll
    for (int off = 32; off; off >>= 1) s += __shfl_down(s, off);
    if (lane == 0) reds[wave] = s;
    __syncthreads();
    if (tid == 0) reds[0] = reds[0] + reds[1] + reds[2] + reds[3];
    __syncthreads();
    const float lse = mx + logf(reds[0]);
    for (int v = tid; v < NV; v += 256) orow[v] = row[v] - lse;
  }
}

// ---------------------------------------------------------------------------
// Gi precompute (all steps), with b_ih folded into the output.
// ---------------------------------------------------------------------------
__global__ __launch_bounds__(256) void gemm_gather(
    const float* __restrict__ emb, const unsigned short* __restrict__ Wiht,
    const float* __restrict__ b_ih,
    unsigned short* __restrict__ Gi, const int* __restrict__ label)
{
  __shared__ unsigned short As[64 * 40];
  __shared__ unsigned short Bs[64 * 40];
  const int tid = threadIdx.x;
  const int rowBase = blockIdx.y * 64, colBase = blockIdx.x * 64;
  const int wave = tid >> 6, lane = tid & 63, quad = lane >> 4, l15 = lane & 15;
  const int rw = (wave & 1) * 32, cw = (wave >> 1) * 32;
  const int K = 256;

  f32x4 acc[2][2];
#pragma unroll
  for (int i = 0; i < 2; ++i)
#pragma unroll
    for (int j = 0; j < 2; ++j)
#pragma unroll
      for (int r = 0; r < 4; ++r) acc[i][j][r] = 0.f;

  const int ar = tid >> 2;
  const int kq = (tid & 3) * 8;
  const int aRowG = rowBase + ar;
  const int t = aRowG >> 9;
  const int b = aRowG & 511;
  const int dec = (t == 0) ? SOS : label[b * LSTR + (t - 1)];
  const float* aptr = emb + (size_t)dec * NE + kq;
  const unsigned short* bptr = Wiht + (size_t)(colBase + ar) * K + kq;
  unsigned short* asd = &As[ar * 40 + kq];
  unsigned short* bsd = &Bs[ar * 40 + kq];

  float4 x0 = *(const float4*)aptr;
  float4 x1 = *(const float4*)(aptr + 4);
  uint4 bv = *(const uint4*)bptr;

  for (int k0 = 0; k0 < K; k0 += 32) {
    uint4 aw;
    aw.x = (unsigned)f2bf(x0.x) | ((unsigned)f2bf(x0.y) << 16);
    aw.y = (unsigned)f2bf(x0.z) | ((unsigned)f2bf(x0.w) << 16);
    aw.z = (unsigned)f2bf(x1.x) | ((unsigned)f2bf(x1.y) << 16);
    aw.w = (unsigned)f2bf(x1.z) | ((unsigned)f2bf(x1.w) << 16);
    *(uint4*)asd = aw;
    *(uint4*)bsd = bv;
    __syncthreads();
    const int kn = k0 + 32;
    if (kn < K) {
      x0 = *(const float4*)(aptr + kn);
      x1 = *(const float4*)(aptr + kn + 4);
      bv = *(const uint4*)(bptr + kn);
    }
    const bf16x8 af0 = *(const bf16x8*)&As[(rw + l15) * 40 + quad * 8];
    const bf16x8 af1 = *(const bf16x8*)&As[(rw + 16 + l15) * 40 + quad * 8];
    const bf16x8 bf0 = *(const bf16x8*)&Bs[(cw + l15) * 40 + quad * 8];
    const bf16x8 bf1 = *(const bf16x8*)&Bs[(cw + 16 + l15) * 40 + quad * 8];
    acc[0][0] = __builtin_amdgcn_mfma_f32_16x16x32_bf16(af0, bf0, acc[0][0], 0, 0, 0);
    acc[0][1] = __builtin_amdgcn_mfma_f32_16x16x32_bf16(af0, bf1, acc[0][1], 0, 0, 0);
    acc[1][0] = __builtin_amdgcn_mfma_f32_16x16x32_bf16(af1, bf0, acc[1][0], 0, 0, 0);
    acc[1][1] = __builtin_amdgcn_mfma_f32_16x16x32_bf16(af1, bf1, acc[1][1], 0, 0, 0);
    __syncthreads();
  }

#pragma unroll
  for (int i = 0; i < 2; ++i) {
    const int grow = rowBase + rw + 16 * i + quad * 4;
#pragma unroll
    for (int j = 0; j < 2; ++j) {
      const int gcol = colBase + cw + 16 * j + l15;
#pragma unroll
      for (int r = 0; r < 4; ++r)
        Gi[(size_t)(grow + r) * 1536 + gcol] = f2bf(acc[i][j][r] + b_ih[gcol]);
    }
  }
}

__global__ void write_last(const int* __restrict__ label, float* __restrict__ out2)
{
  const int b = blockIdx.x * 256 + threadIdx.x;
  if (b < NB) out2[b] = (float)label[b * LSTR + (NT - 1)];
}

__global__ __launch_bounds__(256) void pack_w1(
    const float* __restrict__ Wa, const float* __restrict__ Whh,
    const float* __restrict__ b_hh,
    unsigned short* __restrict__ W1t, float* __restrict__ biasUG)
{
  const int idx = blockIdx.x * 256 + threadIdx.x;
  const int n = idx >> 9, k = idx & 511;
  const float v = (n < NH) ? Wa[k * NH + n] : Whh[(size_t)(n - NH) * NH + k];
  W1t[idx] = f2bf(v);
  if (idx < 2048) biasUG[idx] = (idx < 512) ? 0.f : b_hh[idx - 512];
}

__global__ __launch_bounds__(256) void cast4(
    const float4* __restrict__ in, ushort4* __restrict__ out, int n4)
{
  const int i = blockIdx.x * 256 + threadIdx.x;
  if (i < n4) {
    const float4 x = in[i];
    ushort4 r;
    r.x = f2bf(x.x); r.y = f2bf(x.y); r.z = f2bf(x.z); r.w = f2bf(x.w);
    out[i] = r;
  }
}

extern "C" void kernel_launch(void* const* d_in, const int* in_sizes, int n_in,
                              void* d_out, int out_size, void* d_ws, size_t ws_size,
                              hipStream_t stream)
{
  const float* enc_h  = (const float*)d_in[0];
  const float* enc    = (const float*)d_in[1];
  const int*   label  = (const int*)d_in[2];
  const int*   numprs = (const int*)d_in[3];
  const float* emb    = (const float*)d_in[4];
  const float* W_ih   = (const float*)d_in[5];
  const float* W_hh   = (const float*)d_in[6];
  const float* b_ih   = (const float*)d_in[7];
  const float* b_hh   = (const float*)d_in[8];
  const float* Wa     = (const float*)d_in[9];
  const float* wa_W   = (const float*)d_in[10];
  const float* fc_W   = (const float*)d_in[11];
  const float* fc_b   = (const float*)d_in[12];
  float* out = (float*)d_out;

  float* f = (float*)d_ws;
  float* hB[2];  hB[0] = f; f += NB * NH;  hB[1] = f; f += NB * NH;
  float* ugB[2]; ugB[0] = f; f += NB * 2048; ugB[1] = f; f += NB * 2048;
  float* wkB[2]; wkB[0] = f; f += NB * ND * NH; wkB[1] = f; f += NB * ND * NH;
  float* lgB[2]; lgB[0] = f; f += NB * NVP; lgB[1] = f; f += NB * NVP;
  float* biasUG = f; f += 2048;
  unsigned short* us = (unsigned short*)f;
  unsigned short* W1t  = us; us += 2048 * 512;
  unsigned short* W3t  = us; us += 512 * 1024;
  unsigned short* W4t  = us; us += (size_t)NVP * 512;
  unsigned short* Wiht = us; us += 1536 * 256;
  unsigned short* ccB[2]; ccB[0] = us; us += (size_t)NB * 1024; ccB[1] = us; us += (size_t)NB * 1024;
  unsigned short* aB[2];  aB[0] = us; us += (size_t)NB * 512;  aB[1] = us; us += (size_t)NB * 512;
  unsigned short* Gi   = us; us += (size_t)NT * NB * 1536;
  unsigned short* enc16 = us;

  const dim3 blk(256);

  hipMemcpyAsync(hB[0], enc_h, (size_t)NB * NH * sizeof(float),
                 hipMemcpyDeviceToDevice, stream);

  pack_w1<<<dim3(2048 * 512 / 256), blk, 0, stream>>>(Wa, W_hh, b_hh, W1t, biasUG);
  cast4<<<dim3(512 * 1024 / 4 / 256), blk, 0, stream>>>(
      (const float4*)wa_W, (ushort4*)W3t, 512 * 1024 / 4);
  cast4<<<dim3((NV * 512 / 4 + 255) / 256), blk, 0, stream>>>(
      (const float4*)fc_W, (ushort4*)W4t, NV * 512 / 4);
  hipMemsetAsync(W4t + (size_t)NV * 512, 0, (size_t)(NVP - NV) * 512 * 2, stream);
  cast4<<<dim3(1536 * 256 / 4 / 256), blk, 0, stream>>>(
      (const float4*)W_ih, (ushort4*)Wiht, 1536 * 256 / 4);
  const size_t encElems = (size_t)NB * NS * NH;
  cast4<<<dim3((int)((encElems / 4 + 255) / 256)), blk, 0, stream>>>(
      (const float4*)enc, (ushort4*)enc16, (int)(encElems / 4));
  gemm_gather<<<dim3(24, NT * 8), blk, 0, stream>>>(emb, Wiht, b_ih, Gi, label);

  // prologue: ug_0 = h_0 @ W1t (plain-A), only G1 active
  mega_step<<<dim3(GRID), blk, 0, stream>>>(
      enc16, numprs, W1t, biasUG, Gi,
      ugB[1], ugB[0], hB[0], hB[1],
      wkB[1], wkB[0], ccB[0], ccB[1],
      W3t, aB[1], aB[0], W4t, fc_b,
      lgB[0], lgB[1], out, -4,
      1, 1, 0, 0, 0, 0, 0, 0);

  for (int i = 0; i <= NT + 3; ++i) {
    const int g1 = (i <= NT - 1) ? 1 : 0;
    const int g3 = g1;
    const int g4 = (i >= 1 && i <= NT) ? 1 : 0;
    const int g5 = (i >= 2 && i <= NT + 1) ? 1 : 0;
    const int g6 = (i >= 3 && i <= NT + 2) ? 1 : 0;
    const int g7 = (i >= 4) ? 1 : 0;
    const int gidx = (i <= NT - 1) ? i : (NT - 1);
    mega_step<<<dim3(GRID), blk, 0, stream>>>(
        enc16, numprs, W1t, biasUG, Gi + (size_t)gidx * NB * 1536,
        ugB[i & 1], ugB[(i + 1) & 1],
        hB[i & 1], hB[(i + 1) & 1],
        wkB[(i + 1) & 1], wkB[i & 1],
        ccB[i & 1], ccB[(i + 1) & 1],
        W3t, aB[(i + 1) & 1], aB[i & 1],
        W4t, fc_b, lgB[i & 1], lgB[(i + 1) & 1],
        out, i - 4,
        g1, 0, g1, g3, g4, g5, g6, g7);
  }

  write_last<<<dim3(2), blk, 0, stream>>>(label, out + (size_t)NB * NT * NV);
}

// Round 6
// 1489.291 us; speedup vs baseline: 1.3904x; 1.3904x over previous
//
#include <hip/hip_runtime.h>
#include <hip/hip_fp8.h>
#include <math.h>

typedef __attribute__((ext_vector_type(8))) short bf16x8;
typedef __attribute__((ext_vector_type(4))) float f32x4;

constexpr int NB = 512;
constexpr int NS = 140;
constexpr int NH = 512;
constexpr int NE = 256;
constexpr int NV = 1000;
constexpr int NVP = 1024;   // padded vocab (16 full 64-col tiles)
constexpr int NT = 21;
constexpr int ND = 7;
constexpr int DL = 20;
constexpr int SOS = 2;
constexpr int LSTR = NT + 1;

__device__ __forceinline__ unsigned short f2bf(float f) {
  union { float f; unsigned u; } v; v.f = f;
  unsigned r = v.u + 0x7fffu + ((v.u >> 16) & 1u);
  return (unsigned short)(r >> 16);
}
__device__ __forceinline__ float bf2f(unsigned short h) {
  union { unsigned u; float f; } v; v.u = ((unsigned)h) << 16;
  return v.f;
}
__device__ __forceinline__ float fp8tof(unsigned v) {
  __hip_fp8_e4m3 t; t.__x = (__hip_fp8_storage_t)(v & 0xffu); return (float)t;
}

// ---------------------------------------------------------------------------
// 64x64 MFMA tile body, double-buffered LDS (ONE barrier per K-chunk).
// A16: bf16 A. EPI: 0 none, 1 +bias (guarded col<NV), 2 tanh. OUT16: bf16 out.
// As/Bs each hold 2 x (64*40) ushort buffers.
// ---------------------------------------------------------------------------
template<int A16, int EPI, int OUT16>
__device__ __forceinline__ void gemm_body(
    const float* __restrict__ Af, const unsigned short* __restrict__ Ah,
    const unsigned short* __restrict__ Bt, const float* __restrict__ bias,
    float* __restrict__ C, unsigned short* __restrict__ C16,
    int K, int lda, int ldc, int bx, int by,
    unsigned short* As, unsigned short* Bs)
{
  const int tid = threadIdx.x;
  const int rowBase = by * 64, colBase = bx * 64;
  const int wave = tid >> 6, lane = tid & 63, quad = lane >> 4, l15 = lane & 15;
  const int rw = (wave & 1) * 32, cw = (wave >> 1) * 32;

  f32x4 acc[2][2];
#pragma unroll
  for (int i = 0; i < 2; ++i)
#pragma unroll
    for (int j = 0; j < 2; ++j)
#pragma unroll
      for (int r = 0; r < 4; ++r) acc[i][j][r] = 0.f;

  const int ar = tid >> 2;
  const int kq = (tid & 3) * 8;
  const float* aptrf = nullptr;
  const unsigned short* aptrh = nullptr;
  if (A16) aptrh = Ah + (size_t)(rowBase + ar) * lda + kq;
  else     aptrf = Af + (size_t)(rowBase + ar) * lda + kq;
  const unsigned short* bptr = Bt + (size_t)(colBase + ar) * K + kq;
  unsigned short* asd = &As[ar * 40 + kq];
  unsigned short* bsd = &Bs[ar * 40 + kq];

  float4 x0, x1;
  uint4 av;
  if (A16) {
    av = *(const uint4*)aptrh;
  } else {
    x0 = *(const float4*)aptrf; x1 = *(const float4*)(aptrf + 4);
  }
  uint4 bv = *(const uint4*)bptr;

  int cur = 0;
  for (int k0 = 0; k0 < K; k0 += 32) {
    uint4 aw;
    if (A16) {
      aw = av;
    } else {
      aw.x = (unsigned)f2bf(x0.x) | ((unsigned)f2bf(x0.y) << 16);
      aw.y = (unsigned)f2bf(x0.z) | ((unsigned)f2bf(x0.w) << 16);
      aw.z = (unsigned)f2bf(x1.x) | ((unsigned)f2bf(x1.y) << 16);
      aw.w = (unsigned)f2bf(x1.z) | ((unsigned)f2bf(x1.w) << 16);
    }
    *(uint4*)(asd + cur * 2560) = aw;
    *(uint4*)(bsd + cur * 2560) = bv;

    const int kn = k0 + 32;
    if (kn < K) {
      if (A16) {
        av = *(const uint4*)(aptrh + kn);
      } else {
        x0 = *(const float4*)(aptrf + kn);
        x1 = *(const float4*)(aptrf + kn + 4);
      }
      bv = *(const uint4*)(bptr + kn);
    }
    __syncthreads();

    const unsigned short* Ab = As + cur * 2560;
    const unsigned short* Bb = Bs + cur * 2560;
    const bf16x8 af0 = *(const bf16x8*)&Ab[(rw + l15) * 40 + quad * 8];
    const bf16x8 af1 = *(const bf16x8*)&Ab[(rw + 16 + l15) * 40 + quad * 8];
    const bf16x8 bf0 = *(const bf16x8*)&Bb[(cw + l15) * 40 + quad * 8];
    const bf16x8 bf1 = *(const bf16x8*)&Bb[(cw + 16 + l15) * 40 + quad * 8];
    acc[0][0] = __builtin_amdgcn_mfma_f32_16x16x32_bf16(af0, bf0, acc[0][0], 0, 0, 0);
    acc[0][1] = __builtin_amdgcn_mfma_f32_16x16x32_bf16(af0, bf1, acc[0][1], 0, 0, 0);
    acc[1][0] = __builtin_amdgcn_mfma_f32_16x16x32_bf16(af1, bf0, acc[1][0], 0, 0, 0);
    acc[1][1] = __builtin_amdgcn_mfma_f32_16x16x32_bf16(af1, bf1, acc[1][1], 0, 0, 0);
    cur ^= 1;
  }

#pragma unroll
  for (int i = 0; i < 2; ++i) {
    const int grow = rowBase + rw + 16 * i + quad * 4;
#pragma unroll
    for (int j = 0; j < 2; ++j) {
      const int gcol = colBase + cw + 16 * j + l15;
#pragma unroll
      for (int r = 0; r < 4; ++r) {
        float vo = acc[i][j][r];
        if (EPI == 1) vo += (gcol < NV) ? bias[gcol] : 0.f;
        if (EPI == 2) vo = tanhf(vo);
        if (OUT16) C16[(size_t)(grow + r) * ldc + gcol] = f2bf(vo);
        else       C[(size_t)(grow + r) * ldc + gcol] = vo;
      }
    }
  }
}

// ---------------------------------------------------------------------------
// Fused GEMM launch (iteration i):
//   [0,256):   ug_{i+1} = h_{i+1} @ [Wa | W_hh^T]    fp32 A, fp32 out
//   [256,320): a_{i-1}  = tanh(concat_{i-1} @ W3^T)  bf16 A, bf16 out
//   [320,448): logits_{i-2} = a_{i-2} @ W4^T + b     bf16 A, fp32 out
// ---------------------------------------------------------------------------
__global__ __launch_bounds__(256) void fused_gemms(
    const float* __restrict__ h, const unsigned short* __restrict__ W1t,
    float* __restrict__ ug,
    const unsigned short* __restrict__ concatW,
    const unsigned short* __restrict__ W3t, unsigned short* __restrict__ aOut,
    const unsigned short* __restrict__ aIn,
    const unsigned short* __restrict__ W4t, const float* __restrict__ fc_b,
    float* __restrict__ logitsW,
    int doUg, int doA, int doLog)
{
  __shared__ unsigned short As[2 * 64 * 40];
  __shared__ unsigned short Bs[2 * 64 * 40];
  const int blk = blockIdx.x;
  if (blk < 256) {
    if (!doUg) return;
    gemm_body<0, 0, 0>(h, nullptr, W1t, nullptr, ug, nullptr,
                       512, 512, 2048, blk & 31, blk >> 5, As, Bs);
  } else if (blk < 320) {
    if (!doA) return;
    const int id = blk - 256;
    gemm_body<1, 2, 1>(nullptr, concatW, W3t, nullptr, nullptr, aOut,
                       1024, 1024, 512, id & 7, id >> 3, As, Bs);
  } else {
    if (!doLog) return;
    const int id = blk - 320;
    gemm_body<1, 1, 0>(nullptr, aIn, W4t, fc_b, logitsW, nullptr,
                       512, 512, NVP, id & 15, id >> 4, As, Bs);
  }
}

// ---------------------------------------------------------------------------
// Gi precompute: all 21 steps of emb[dec_t] @ W_ih^T, bf16 out. 2D grid.
// ---------------------------------------------------------------------------
__global__ __launch_bounds__(256) void gemm_gather(
    const float* __restrict__ emb, const unsigned short* __restrict__ Wiht,
    unsigned short* __restrict__ Gi, const int* __restrict__ label)
{
  __shared__ unsigned short As[64 * 40];
  __shared__ unsigned short Bs[64 * 40];
  const int tid = threadIdx.x;
  const int rowBase = blockIdx.y * 64, colBase = blockIdx.x * 64;
  const int wave = tid >> 6, lane = tid & 63, quad = lane >> 4, l15 = lane & 15;
  const int rw = (wave & 1) * 32, cw = (wave >> 1) * 32;
  const int K = 256;

  f32x4 acc[2][2];
#pragma unroll
  for (int i = 0; i < 2; ++i)
#pragma unroll
    for (int j = 0; j < 2; ++j)
#pragma unroll
      for (int r = 0; r < 4; ++r) acc[i][j][r] = 0.f;

  const int ar = tid >> 2;
  const int kq = (tid & 3) * 8;
  const int aRowG = rowBase + ar;
  const int t = aRowG >> 9;
  const int b = aRowG & 511;
  const int dec = (t == 0) ? SOS : label[b * LSTR + (t - 1)];
  const float* aptr = emb + (size_t)dec * NE + kq;
  const unsigned short* bptr = Wiht + (size_t)(colBase + ar) * K + kq;
  unsigned short* asd = &As[ar * 40 + kq];
  unsigned short* bsd = &Bs[ar * 40 + kq];

  float4 x0 = *(const float4*)aptr;
  float4 x1 = *(const float4*)(aptr + 4);
  uint4 bv = *(const uint4*)bptr;

  for (int k0 = 0; k0 < K; k0 += 32) {
    uint4 aw;
    aw.x = (unsigned)f2bf(x0.x) | ((unsigned)f2bf(x0.y) << 16);
    aw.y = (unsigned)f2bf(x0.z) | ((unsigned)f2bf(x0.w) << 16);
    aw.z = (unsigned)f2bf(x1.x) | ((unsigned)f2bf(x1.y) << 16);
    aw.w = (unsigned)f2bf(x1.z) | ((unsigned)f2bf(x1.w) << 16);
    *(uint4*)asd = aw;
    *(uint4*)bsd = bv;
    __syncthreads();
    const int kn = k0 + 32;
    if (kn < K) {
      x0 = *(const float4*)(aptr + kn);
      x1 = *(const float4*)(aptr + kn + 4);
      bv = *(const uint4*)(bptr + kn);
    }
    const bf16x8 af0 = *(const bf16x8*)&As[(rw + l15) * 40 + quad * 8];
    const bf16x8 af1 = *(const bf16x8*)&As[(rw + 16 + l15) * 40 + quad * 8];
    const bf16x8 bf0 = *(const bf16x8*)&Bs[(cw + l15) * 40 + quad * 8];
    const bf16x8 bf1 = *(const bf16x8*)&Bs[(cw + 16 + l15) * 40 + quad * 8];
    acc[0][0] = __builtin_amdgcn_mfma_f32_16x16x32_bf16(af0, bf0, acc[0][0], 0, 0, 0);
    acc[0][1] = __builtin_amdgcn_mfma_f32_16x16x32_bf16(af0, bf1, acc[0][1], 0, 0, 0);
    acc[1][0] = __builtin_amdgcn_mfma_f32_16x16x32_bf16(af1, bf0, acc[1][0], 0, 0, 0);
    acc[1][1] = __builtin_amdgcn_mfma_f32_16x16x32_bf16(af1, bf1, acc[1][1], 0, 0, 0);
    __syncthreads();
  }

#pragma unroll
  for (int i = 0; i < 2; ++i) {
    const int grow = rowBase + rw + 16 * i + quad * 4;
#pragma unroll
    for (int j = 0; j < 2; ++j) {
      const int gcol = colBase + cw + 16 * j + l15;
#pragma unroll
      for (int r = 0; r < 4; ++r)
        Gi[(size_t)(grow + r) * 1536 + gcol] = f2bf(acc[i][j][r]);
    }
  }
}

// ---------------------------------------------------------------------------
// Misc fused launch (iteration i):
//   [0,3584):     day_{i+1}  (fp8 enc in LDS, wave-parallel softmax(20))
//   [3584,4608):  gru_{i+1}
//   [4608,4640):  ctxcat_i
//   [4640,5152):  lsm_{i-2}
// ---------------------------------------------------------------------------
__global__ __launch_bounds__(256) void step_misc(
    const unsigned char* __restrict__ enc8, const float* __restrict__ ug,
    const int* __restrict__ numpairs, const unsigned short* __restrict__ giT,
    const float* __restrict__ b_ih, const float* __restrict__ b_hh,
    const float* __restrict__ hRead, float* __restrict__ hWrite,
    const float* __restrict__ weekRead, float* __restrict__ weekWrite,
    unsigned short* __restrict__ concatW,
    const float* __restrict__ logitsW, float* __restrict__ out, int tOut,
    int doDay, int doCtx, int doLsm)
{
  __shared__ __align__(16) char smem[12544];
  const int blk = blockIdx.x;
  const int tid = threadIdx.x;
  const int wave = tid >> 6, lane = tid & 63;

  if (blk < NB * ND) {
    // ---------------- day attention (t = i+1), fp8 enc ----------------
    if (!doDay) return;
    unsigned char* enc8s = (unsigned char*)smem;           // 10240 B
    float* uS  = (float*)(smem + 10240);                   // 2048 B
    float* scD = (float*)(smem + 12288);                   // 80 B
    float* wdD = (float*)(smem + 12368);                   // 80 B
    const int b = blk / ND, d = blk % ND;

    const uint4* ep = (const uint4*)(enc8 + ((size_t)b * NS + d * DL) * NH);
    uint4* dst = (uint4*)enc8s;
    for (int i = tid; i < DL * NH / 16; i += 256) dst[i] = ep[i];
    if (tid < NH / 4)
      ((float4*)uS)[tid] = ((const float4*)(ug + (size_t)b * 2048))[tid];
    __syncthreads();

    float u8[8];
    {
      float4 a = *(const float4*)(uS + lane * 8);
      float4 c = *(const float4*)(uS + lane * 8 + 4);
      u8[0] = a.x; u8[1] = a.y; u8[2] = a.z; u8[3] = a.w;
      u8[4] = c.x; u8[5] = c.y; u8[6] = c.z; u8[7] = c.w;
    }
#pragma unroll
    for (int si = 0; si < 5; ++si) {
      const int s = wave * 5 + si;
      const unsigned char* er = enc8s + s * NH + lane * 8;
      const unsigned v0 = *(const unsigned*)er;
      const unsigned v1 = *(const unsigned*)(er + 4);
      float p = fp8tof(v0) * u8[0] + fp8tof(v0 >> 8) * u8[1] +
                fp8tof(v0 >> 16) * u8[2] + fp8tof(v0 >> 24) * u8[3] +
                fp8tof(v1) * u8[4] + fp8tof(v1 >> 8) * u8[5] +
                fp8tof(v1 >> 16) * u8[6] + fp8tof(v1 >> 24) * u8[7];
#pragma unroll
      for (int off = 32; off; off >>= 1) p += __shfl_down(p, off);
      if (lane == 0) scD[s] = p;
    }
    __syncthreads();
    if (wave == 0) {
      float v = -1e30f;
      if (lane < DL) {
        v = scD[lane];
        if (numpairs[b * NS + d * DL + lane] == 0) v = -1e9f;
      }
      float mx = v;
#pragma unroll
      for (int off = 32; off; off >>= 1) mx = fmaxf(mx, __shfl_xor(mx, off));
      const float e = (lane < DL) ? expf(v - mx) : 0.f;
      float sm = e;
#pragma unroll
      for (int off = 32; off; off >>= 1) sm += __shfl_xor(sm, off);
      if (lane < DL) wdD[lane] = e / sm;
    }
    __syncthreads();
    float a0 = 0.f, a1 = 0.f;
#pragma unroll
    for (int s = 0; s < DL; ++s) {
      const float w = wdD[s];
      const unsigned pv = *(const unsigned short*)&enc8s[s * NH + tid * 2];
      a0 += w * fp8tof(pv);
      a1 += w * fp8tof(pv >> 8);
    }
    float2 r; r.x = a0; r.y = a1;
    *(float2*)(weekWrite + ((size_t)b * ND + d) * NH + tid * 2) = r;
  } else if (blk < NB * ND + 1024) {
    // ---------------- GRU (t = i+1) ----------------
    if (!doDay) return;
    const int idx = (blk - NB * ND) * 256 + tid;
    const int b = idx >> 9, j = idx & (NH - 1);
    const unsigned short* gib = giT + (size_t)b * 1536;
    const float* ghb = ug + (size_t)b * 2048 + NH;
    const float ir  = bf2f(gib[j]) + b_ih[j];
    const float iz  = bf2f(gib[NH + j]) + b_ih[NH + j];
    const float in_ = bf2f(gib[2 * NH + j]) + b_ih[2 * NH + j];
    const float hr  = ghb[j] + b_hh[j];
    const float hz  = ghb[NH + j] + b_hh[NH + j];
    const float hn_ = ghb[2 * NH + j] + b_hh[2 * NH + j];
    const float rg = 1.f / (1.f + expf(-(ir + hr)));
    const float zg = 1.f / (1.f + expf(-(iz + hz)));
    const float ng = tanhf(in_ + rg * hn_);
    hWrite[idx] = (1.f - zg) * ng + zg * hRead[idx];
  } else if (blk < NB * ND + 1024 + 32) {
    // ---------------- ctx + concat (t = i) ----------------
    if (!doCtx) return;
    float* scS = (float*)smem;            // 16*7
    float* awS = (float*)(smem + 448);    // 16*7
    const int rbase = (blk - NB * ND - 1024) * 16;
    const int b16 = tid >> 4, k16 = tid & 15;
    const int b = rbase + b16;
    const float* vrow = ug + (size_t)b * 2048;       // v_i = u_{i+1}
    const float* wrow = weekRead + (size_t)b * ND * NH;

    for (int d = 0; d < ND; ++d) {
      const float* vp = vrow + k16 * 32;
      const float* wp = wrow + d * NH + k16 * 32;
      float p = 0.f;
#pragma unroll
      for (int q = 0; q < 8; ++q) {
        float4 a = *(const float4*)(vp + q * 4);
        float4 c = *(const float4*)(wp + q * 4);
        p += a.x * c.x + a.y * c.y + a.z * c.z + a.w * c.w;
      }
      p += __shfl_down(p, 8); p += __shfl_down(p, 4);
      p += __shfl_down(p, 2); p += __shfl_down(p, 1);
      if (k16 == 0) scS[b16 * ND + d] = p;
    }
    __syncthreads();
    if (tid < 16) {
      float s[ND], mx = -1e30f;
      for (int d = 0; d < ND; ++d) { s[d] = scS[tid * ND + d]; mx = fmaxf(mx, s[d]); }
      float sum = 0.f;
      for (int d = 0; d < ND; ++d) { float e = expf(s[d] - mx); s[d] = e; sum += e; }
      const float inv = 1.f / sum;
      for (int d = 0; d < ND; ++d) awS[tid * ND + d] = s[d] * inv;
    }
    __syncthreads();

    const int c0 = k16 * 32;
    const float* hp = hRead + (size_t)b * NH + c0;
    float aw[ND];
#pragma unroll
    for (int d = 0; d < ND; ++d) aw[d] = awS[b16 * ND + d];
    unsigned short* crow = concatW + (size_t)b * 1024;
#pragma unroll
    for (int q = 0; q < 8; ++q) {
      const int c = c0 + q * 4;
      float4 hv = *(const float4*)(hp + q * 4);
      ushort4 hs;
      hs.x = f2bf(hv.x); hs.y = f2bf(hv.y); hs.z = f2bf(hv.z); hs.w = f2bf(hv.w);
      *(ushort4*)(crow + c) = hs;
      float4 cv = make_float4(0.f, 0.f, 0.f, 0.f);
#pragma unroll
      for (int d = 0; d < ND; ++d) {
        float4 wv = *(const float4*)(wrow + d * NH + c);
        cv.x += aw[d] * wv.x; cv.y += aw[d] * wv.y;
        cv.z += aw[d] * wv.z; cv.w += aw[d] * wv.w;
      }
      ushort4 cs;
      cs.x = f2bf(cv.x); cs.y = f2bf(cv.y); cs.z = f2bf(cv.z); cs.w = f2bf(cv.w);
      *(ushort4*)(crow + 512 + c) = cs;
    }
  } else {
    // ---------------- log_softmax (t = i-2) ----------------
    if (!doLsm) return;
    float* redm = (float*)smem;
    float* reds = (float*)(smem + 64);
    const int b = blk - (NB * ND + 1024 + 32);
    const float* row = logitsW + (size_t)b * NVP;
    float* orow = out + (size_t)b * NT * NV + (size_t)tOut * NV;

    float mx = -1e30f;
    for (int v = tid; v < NV; v += 256) mx = fmaxf(mx, row[v]);
#pragma unroll
    for (int off = 32; off; off >>= 1) mx = fmaxf(mx, __shfl_down(mx, off));
    if (lane == 0) redm[wave] = mx;
    __syncthreads();
    if (tid == 0) redm[0] = fmaxf(fmaxf(redm[0], redm[1]), fmaxf(redm[2], redm[3]));
    __syncthreads();
    mx = redm[0];

    float s = 0.f;
    for (int v = tid; v < NV; v += 256) s += expf(row[v] - mx);
#pragma unroll
    for (int off = 32; off; off >>= 1) s += __shfl_down(s, off);
    if (lane == 0) reds[wave] = s;
    __syncthreads();
    if (tid == 0) reds[0] = reds[0] + reds[1] + reds[2] + reds[3];
    __syncthreads();
    const float lse = mx + logf(reds[0]);
    for (int v = tid; v < NV; v += 256) orow[v] = row[v] - lse;
  }
}

__global__ void write_last(const int* __restrict__ label, float* __restrict__ out2)
{
  const int b = blockIdx.x * 256 + threadIdx.x;
  if (b < NB) out2[b] = (float)label[b * LSTR + (NT - 1)];
}

__global__ __launch_bounds__(256) void pack_w1(
    const float* __restrict__ Wa, const float* __restrict__ Whh,
    unsigned short* __restrict__ W1t)
{
  const int idx = blockIdx.x * 256 + threadIdx.x;
  const int n = idx >> 9, k = idx & 511;
  const float v = (n < NH) ? Wa[k * NH + n] : Whh[(size_t)(n - NH) * NH + k];
  W1t[idx] = f2bf(v);
}

__global__ __launch_bounds__(256) void cast4(
    const float4* __restrict__ in, ushort4* __restrict__ out, int n4)
{
  const int i = blockIdx.x * 256 + threadIdx.x;
  if (i < n4) {
    const float4 x = in[i];
    ushort4 r;
    r.x = f2bf(x.x); r.y = f2bf(x.y); r.z = f2bf(x.z); r.w = f2bf(x.w);
    out[i] = r;
  }
}

__global__ __launch_bounds__(256) void cast_fp8(
    const float4* __restrict__ in, uchar4* __restrict__ out, int n4)
{
  const int i = blockIdx.x * 256 + threadIdx.x;
  if (i < n4) {
    const float4 x = in[i];
    __hip_fp8_e4m3 a(x.x), b(x.y), c(x.z), d(x.w);
    uchar4 r;
    r.x = a.__x; r.y = b.__x; r.z = c.__x; r.w = d.__x;
    out[i] = r;
  }
}

extern "C" void kernel_launch(void* const* d_in, const int* in_sizes, int n_in,
                              void* d_out, int out_size, void* d_ws, size_t ws_size,
                              hipStream_t stream)
{
  const float* enc_h  = (const float*)d_in[0];
  const float* enc    = (const float*)d_in[1];
  const int*   label  = (const int*)d_in[2];
  const int*   numprs = (const int*)d_in[3];
  const float* emb    = (const float*)d_in[4];
  const float* W_ih   = (const float*)d_in[5];
  const float* W_hh   = (const float*)d_in[6];
  const float* b_ih   = (const float*)d_in[7];
  const float* b_hh   = (const float*)d_in[8];
  const float* Wa     = (const float*)d_in[9];
  const float* wa_W   = (const float*)d_in[10];
  const float* fc_W   = (const float*)d_in[11];
  const float* fc_b   = (const float*)d_in[12];
  float* out = (float*)d_out;

  float* f = (float*)d_ws;
  float* H0  = f; f += NB * NH;
  float* H1  = f; f += NB * NH;
  float* ug  = f; f += NB * 2048;
  float* wkb[2];
  wkb[0] = f; f += NB * ND * NH;
  wkb[1] = f; f += NB * ND * NH;
  float* logitsW = f; f += NB * NVP;
  unsigned short* us = (unsigned short*)f;
  unsigned short* W1t    = us; us += 2048 * 512;
  unsigned short* W3t    = us; us += 512 * 1024;
  unsigned short* W4t    = us; us += (size_t)NVP * 512;
  unsigned short* Wiht   = us; us += 1536 * 256;
  unsigned short* concatW= us; us += (size_t)NB * 1024;
  unsigned short* aBuf0  = us; us += (size_t)NB * 512;
  unsigned short* aBuf1  = us; us += (size_t)NB * 512;
  unsigned short* Gi     = us; us += (size_t)NT * NB * 1536;
  unsigned char* enc8    = (unsigned char*)us;   // NB*NS*NH bytes
  unsigned short* aBuf[2] = {aBuf0, aBuf1};

  const dim3 blk(256);
  float* H[2] = {H0, H1};

  hipMemcpyAsync(H0, enc_h, (size_t)NB * NH * sizeof(float),
                 hipMemcpyDeviceToDevice, stream);

  pack_w1<<<dim3(2048 * 512 / 256), blk, 0, stream>>>(Wa, W_hh, W1t);
  cast4<<<dim3(512 * 1024 / 4 / 256), blk, 0, stream>>>(
      (const float4*)wa_W, (ushort4*)W3t, 512 * 1024 / 4);
  cast4<<<dim3((NV * 512 / 4 + 255) / 256), blk, 0, stream>>>(
      (const float4*)fc_W, (ushort4*)W4t, NV * 512 / 4);
  hipMemsetAsync(W4t + (size_t)NV * 512, 0, (size_t)(NVP - NV) * 512 * 2, stream);
  cast4<<<dim3(1536 * 256 / 4 / 256), blk, 0, stream>>>(
      (const float4*)W_ih, (ushort4*)Wiht, 1536 * 256 / 4);
  const size_t encElems = (size_t)NB * NS * NH;
  cast_fp8<<<dim3((int)((encElems / 4 + 255) / 256)), blk, 0, stream>>>(
      (const float4*)enc, (uchar4*)enc8, (int)(encElems / 4));
  gemm_gather<<<dim3(24, NT * 8), blk, 0, stream>>>(emb, Wiht, Gi, label);

  const int miscGrid = NB * ND + 1024 + 32 + NB;  // 5152

  // Software-pipelined loop.  At iteration i:
  //   K_A: ug_{i+1} | aGEMM_{i-1} | logitsGEMM_{i-2}
  //   K_B: day_{i+1} + gru_{i+1} | ctxcat_i | lsm_{i-2}
  for (int i = -1; i <= NT + 1; ++i) {
    const int doUg  = (i <= NT - 1) ? 1 : 0;
    const int doA   = (i >= 1 && i <= NT) ? 1 : 0;
    const int doLog = (i >= 2) ? 1 : 0;
    if (doUg || doA || doLog)
      fused_gemms<<<dim3(448), blk, 0, stream>>>(
          H[(i + 1) & 1], W1t, ug,
          concatW, W3t, aBuf[(i + 1) & 1],
          aBuf[i & 1], W4t, fc_b, logitsW,
          doUg, doA, doLog);

    const int doDay = (i <= NT - 2) ? 1 : 0;
    const int doCtx = (i >= 0 && i <= NT - 1) ? 1 : 0;
    const int doLsm = (i >= 2) ? 1 : 0;
    int giIdx = i + 1;
    if (giIdx < 0) giIdx = 0;
    if (giIdx > NT - 1) giIdx = NT - 1;
    step_misc<<<dim3(miscGrid), blk, 0, stream>>>(
        enc8, ug, numprs, Gi + (size_t)giIdx * NB * 1536,
        b_ih, b_hh, H[(i + 1) & 1], H[i & 1],
        wkb[i & 1], wkb[(i + 1) & 1], concatW,
        logitsW, out, i - 2, doDay, doCtx, doLsm);
  }

  write_last<<<dim3(2), blk, 0, stream>>>(label, out + (size_t)NB * NT * NV);
}